// Round 1
// baseline (222.361 us; speedup 1.0000x reference)
//
#include <hip/hip_runtime.h>
#include <stdint.h>

typedef __attribute__((ext_vector_type(4))) float f32x4;
typedef __attribute__((ext_vector_type(8))) __bf16 bf16x8;
typedef __attribute__((ext_vector_type(4))) unsigned int u32x4;
typedef unsigned short u16;

#define B_DIM 2
#define T_DIM 2048
#define C_DIM 2048
#define H_Q   16
#define H_KV  4
#define HD    128
#define NQKV  3072            // 2048 q | 512 k | 512 v
#define MTOK  4096            // B*T
#define RMS_EPS 1.1920928955078125e-07f

__device__ __forceinline__ u16 f2bf(float f) {
  union { float f; unsigned int u; } v; v.f = f;
  unsigned int r = v.u + 0x7FFFu + ((v.u >> 16) & 1u);   // RNE
  return (u16)(r >> 16);
}
__device__ __forceinline__ float bf2f(u16 h) {
  union { unsigned int u; float f; } v; v.u = ((unsigned int)h) << 16;
  return v.f;
}
__device__ __forceinline__ f32x4 mfma16(bf16x8 a, bf16x8 b, f32x4 c) {
  return __builtin_amdgcn_mfma_f32_16x16x32_bf16(a, b, c, 0, 0, 0);
}

// ---------------- cast x fp32 -> bf16 ----------------
__global__ __launch_bounds__(256) void cast_x_kernel(const float* __restrict__ x,
                                                     u16* __restrict__ xb, int n) {
  int i = (blockIdx.x * 256 + threadIdx.x) * 4;
  if (i >= n) return;
  float4 v = *(const float4*)(x + i);
  u16 o0 = f2bf(v.x), o1 = f2bf(v.y), o2 = f2bf(v.z), o3 = f2bf(v.w);
  unsigned int lo = (unsigned int)o0 | ((unsigned int)o1 << 16);
  unsigned int hi = (unsigned int)o2 | ((unsigned int)o3 << 16);
  *(uint2*)(xb + i) = make_uint2(lo, hi);
}

// ---------------- transpose + cast: in fp32 [K][N] -> out bf16 [N][K] ----------------
__global__ __launch_bounds__(256) void transpose_cast_kernel(const float* __restrict__ in,
                                                             u16* __restrict__ out,
                                                             int K, int N) {
  __shared__ float tile[64][65];           // +1 pad: conflict-free transposed reads
  int n0 = blockIdx.x * 64, k0 = blockIdx.y * 64;
  int t = threadIdx.x;
  #pragma unroll
  for (int idx = t; idx < 4096; idx += 256) {
    int r = idx >> 6, c = idx & 63;        // r = k-local, c = n-local
    tile[r][c] = in[(size_t)(k0 + r) * N + n0 + c];
  }
  __syncthreads();
  #pragma unroll
  for (int idx = t; idx < 4096; idx += 256) {
    int r = idx >> 6, c = idx & 63;        // r = n-local, c = k-local
    out[(size_t)(n0 + r) * K + k0 + c] = f2bf(tile[c][r]);
  }
}

// ---------------- RoPE + RMS-norm in place on q,k columns of qkv (bf16) ----------------
__global__ __launch_bounds__(256) void rope_rms_kernel(u16* __restrict__ qkv,
                                                       const float* __restrict__ cosb,
                                                       const float* __restrict__ sinb) {
  int gw = (blockIdx.x * 256 + threadIdx.x) >> 6;   // one wave per (token, head)
  int lane = threadIdx.x & 63;
  int hh = gw % (H_Q + H_KV);
  int tok = gw / (H_Q + H_KV);
  int t = tok & (T_DIM - 1);
  int base = (hh < H_Q) ? hh * HD : (C_DIM + (hh - H_Q) * HD);
  u16* p = qkv + (size_t)tok * NQKV + base;
  float x1 = bf2f(p[lane]);
  float x2 = bf2f(p[lane + 64]);
  float c = cosb[t * 64 + lane];
  float s = sinb[t * 64 + lane];
  float o1 =  x1 * c + x2 * s;
  float o2 = -x1 * s + x2 * c;
  float ss = o1 * o1 + o2 * o2;
  #pragma unroll
  for (int off = 1; off < 64; off <<= 1) ss += __shfl_xor(ss, off);
  float r = rsqrtf(ss * (1.0f / 128.0f) + RMS_EPS);
  p[lane]      = f2bf(o1 * r);
  p[lane + 64] = f2bf(o2 * r);
}

// ---------------- bf16 GEMM: C[M][N] = A[M][K] * Bt[N][K]^T ----------------
// 128x128 tile, BK=64, 4 waves (2x2 of 64x64), 16x16x32 MFMA.
// LDS rows are 8 chunks of 16B; chunk swizzle c' = c ^ (row&7) -> conflict-free frag reads.
template<int BF16OUT>
__global__ __launch_bounds__(256) void gemm_bt_kernel(const u16* __restrict__ A,
                                                      const u16* __restrict__ Bt,
                                                      void* __restrict__ Cv,
                                                      int M, int N, int K) {
  __shared__ __align__(16) u16 Asm[128 * 64];
  __shared__ __align__(16) u16 Bsm[128 * 64];
  const int tid = threadIdx.x;
  const int lane = tid & 63;
  const int wid = tid >> 6;
  const int m0 = blockIdx.y * 128, n0 = blockIdx.x * 128;
  const int wm = (wid >> 1) * 64, wn = (wid & 1) * 64;
  const int l15 = lane & 15, l4 = lane >> 4;
  f32x4 acc[4][4] = {};

  for (int k0 = 0; k0 < K; k0 += 64) {
    __syncthreads();
    #pragma unroll
    for (int i = 0; i < 4; ++i) {          // 1024 16B chunks per operand tile
      int cid = tid + i * 256;
      int row = cid >> 3, c = cid & 7;
      int dst = row * 128 + ((c ^ (row & 7)) * 16);
      u32x4 va = *(const u32x4*)(A  + (size_t)(m0 + row) * K + k0 + c * 8);
      *(u32x4*)((char*)Asm + dst) = va;
      u32x4 vb = *(const u32x4*)(Bt + (size_t)(n0 + row) * K + k0 + c * 8);
      *(u32x4*)((char*)Bsm + dst) = vb;
    }
    __syncthreads();
    #pragma unroll
    for (int ks = 0; ks < 2; ++ks) {
      bf16x8 af[4], bfr[4];
      #pragma unroll
      for (int mf = 0; mf < 4; ++mf) {
        int r = wm + mf * 16 + l15;
        int bo = r * 128 + (((ks * 4 + l4) ^ (r & 7)) * 16);
        af[mf] = __builtin_bit_cast(bf16x8, *(const u32x4*)((const char*)Asm + bo));
      }
      #pragma unroll
      for (int nf = 0; nf < 4; ++nf) {
        int r = wn + nf * 16 + l15;
        int bo = r * 128 + (((ks * 4 + l4) ^ (r & 7)) * 16);
        bfr[nf] = __builtin_bit_cast(bf16x8, *(const u32x4*)((const char*)Bsm + bo));
      }
      #pragma unroll
      for (int mf = 0; mf < 4; ++mf)
        #pragma unroll
        for (int nf = 0; nf < 4; ++nf)
          acc[mf][nf] = mfma16(af[mf], bfr[nf], acc[mf][nf]);
    }
  }
  // epilogue: C/D layout col = lane&15, row = (lane>>4)*4 + reg  [m89-verified]
  #pragma unroll
  for (int mf = 0; mf < 4; ++mf)
    #pragma unroll
    for (int nf = 0; nf < 4; ++nf)
      #pragma unroll
      for (int reg = 0; reg < 4; ++reg) {
        int row = m0 + wm + mf * 16 + l4 * 4 + reg;
        int col = n0 + wn + nf * 16 + l15;
        float v = acc[mf][nf][reg];
        if (BF16OUT) ((u16*)Cv)[(size_t)row * N + col] = f2bf(v);
        else         ((float*)Cv)[(size_t)row * N + col] = v;
      }
}

// ---------------- sliding-window GQA flash attention ----------------
// Block = 64 q-rows of one (b,h); 4 waves, 16 rows each. K-tiles of 64.
__global__ __launch_bounds__(256) void attn_kernel(const u16* __restrict__ qkv,
                                                   u16* __restrict__ yb,
                                                   const int* __restrict__ wsz_p) {
  __shared__ __align__(16) u16 Ksm[64 * 128];    // [key][d], chunk-swizzled
  __shared__ __align__(16) u16 Vsm[128 * 64];    // [d][key] (transposed), swizzled
  __shared__ __align__(16) u16 Psm[4 * 16 * 64]; // per-wave P, swizzled

  const int W = wsz_p[0];
  const int tid = threadIdx.x, lane = tid & 63, wid = tid >> 6;
  const int l15 = lane & 15, l4 = lane >> 4;
  const int bid = blockIdx.x;
  const int qt  = bid & 31;              // T/64
  const int h   = (bid >> 5) & 15;
  const int b   = bid >> 9;
  const int kvh = h >> 2;                // rep = 4
  const size_t tokb = (size_t)b * T_DIM;

  // Q fragments (A-layout: row = lane&15, k = (lane>>4)*8 + j)
  bf16x8 qf[4];
  {
    int r = qt * 64 + wid * 16 + l15;
    const u16* qp = qkv + (tokb + r) * NQKV + h * HD;
    #pragma unroll
    for (int ks = 0; ks < 4; ++ks)
      qf[ks] = __builtin_bit_cast(bf16x8, *(const u32x4*)(qp + ks * 32 + l4 * 8));
  }

  f32x4 yacc[8] = {};
  float mrow[4], lrow[4];
  #pragma unroll
  for (int rg = 0; rg < 4; ++rg) { mrow[rg] = -3.0e38f; lrow[rg] = 0.0f; }

  const float sc = 0.08838834764831845f * 1.4426950408889634f; // 1/sqrt(128) * log2(e)
  const int rbase = qt * 64 + wid * 16;
  int smin = qt * 64 - W; if (smin < 0) smin = 0;
  const int t0 = smin >> 6;

  for (int kt = t0; kt <= qt; ++kt) {
    __syncthreads();
    { // stage K: [key][16 chunks], swizzle c^(key&7)
      const u16* kp = qkv + (tokb + kt * 64) * NQKV + C_DIM + kvh * HD;
      #pragma unroll
      for (int i = 0; i < 4; ++i) {
        int cid = tid + i * 256;
        int key = cid >> 4, c = cid & 15;
        u32x4 v = *(const u32x4*)(kp + (size_t)key * NQKV + c * 8);
        *(u32x4*)((char*)Ksm + key * 256 + ((c ^ (key & 7)) * 16)) = v;
      }
    }
    { // stage V transposed: read column d over 8 keys, write [d][keychunk] swizzled
      const u16* vp = qkv + (tokb + kt * 64) * NQKV + C_DIM + H_KV * HD + kvh * HD;
      int d = tid & 127, g = tid >> 7;
      #pragma unroll
      for (int cc = 0; cc < 4; ++cc) {
        int kc = g * 4 + cc;
        u16 vals[8];
        #pragma unroll
        for (int j = 0; j < 8; ++j)
          vals[j] = vp[(size_t)(kc * 8 + j) * NQKV + d];
        u32x4 w;
        w.x = (unsigned int)vals[0] | ((unsigned int)vals[1] << 16);
        w.y = (unsigned int)vals[2] | ((unsigned int)vals[3] << 16);
        w.z = (unsigned int)vals[4] | ((unsigned int)vals[5] << 16);
        w.w = (unsigned int)vals[6] | ((unsigned int)vals[7] << 16);
        *(u32x4*)((char*)Vsm + d * 128 + ((kc ^ (d & 7)) * 16)) = w;
      }
    }
    __syncthreads();

    // S = Q K^T  (16 q-rows x 64 keys per wave)
    float Sc[4][4];
    #pragma unroll
    for (int nf = 0; nf < 4; ++nf) {
      f32x4 sa = {0.f, 0.f, 0.f, 0.f};
      int key = nf * 16 + l15;
      #pragma unroll
      for (int ks = 0; ks < 4; ++ks) {
        int bo = key * 256 + (((ks * 4 + l4) ^ (key & 7)) * 16);
        bf16x8 kf = __builtin_bit_cast(bf16x8, *(const u32x4*)((const char*)Ksm + bo));
        sa = mfma16(qf[ks], kf, sa);
      }
      #pragma unroll
      for (int rg = 0; rg < 4; ++rg) Sc[nf][rg] = sa[rg] * sc;
    }

    // mask (only when tile not fully valid for this wave)
    const int slo = kt * 64;
    bool fullvalid = ((slo + 63) <= rbase) && ((rbase + 15 - slo) <= W);
    if (!fullvalid) {
      #pragma unroll
      for (int nf = 0; nf < 4; ++nf) {
        int s = slo + nf * 16 + l15;
        #pragma unroll
        for (int rg = 0; rg < 4; ++rg) {
          int r = rbase + l4 * 4 + rg;
          if (s > r || (r - s) > W) Sc[nf][rg] = -3.0e38f;
        }
      }
    }

    // online softmax (exp2 domain); clamp guards all-masked boundary tiles
    float f[4];
    #pragma unroll
    for (int rg = 0; rg < 4; ++rg) {
      float tm = fmaxf(fmaxf(Sc[0][rg], Sc[1][rg]), fmaxf(Sc[2][rg], Sc[3][rg]));
      #pragma unroll
      for (int off = 1; off < 16; off <<= 1) tm = fmaxf(tm, __shfl_xor(tm, off));
      float mnew = fmaxf(mrow[rg], tm);
      float mo = fmaxf(mrow[rg], -1.0e30f);
      float mc = fmaxf(mnew,     -1.0e30f);
      f[rg] = exp2f(mo - mc);
      mrow[rg] = mnew;
    }
    float rs[4] = {0.f, 0.f, 0.f, 0.f};
    u16 pb[4][4];
    #pragma unroll
    for (int nf = 0; nf < 4; ++nf)
      #pragma unroll
      for (int rg = 0; rg < 4; ++rg) {
        float mc = fmaxf(mrow[rg], -1.0e30f);
        float pv = exp2f(Sc[nf][rg] - mc);
        rs[rg] += pv;
        pb[nf][rg] = f2bf(pv);
      }
    #pragma unroll
    for (int rg = 0; rg < 4; ++rg) {
      #pragma unroll
      for (int off = 1; off < 16; off <<= 1) rs[rg] += __shfl_xor(rs[rg], off);
      lrow[rg] = lrow[rg] * f[rg] + rs[rg];
    }
    f32x4 fv = {f[0], f[1], f[2], f[3]};
    #pragma unroll
    for (int nf2 = 0; nf2 < 8; ++nf2) yacc[nf2] *= fv;

    // P -> wave-private LDS (bf16, swizzled for A-frag reads)
    char* pbase = (char*)Psm + wid * 2048;
    #pragma unroll
    for (int nf = 0; nf < 4; ++nf)
      #pragma unroll
      for (int rg = 0; rg < 4; ++rg) {
        int q   = l4 * 4 + rg;
        int key = nf * 16 + l15;
        int bo = q * 128 + ((((key >> 3) ^ (q & 7)) * 16) + (key & 7) * 2);
        *(u16*)(pbase + bo) = pb[nf][rg];
      }

    // PV: y(16 x 128) += P(16 x 64) @ V(64 x 128)
    #pragma unroll
    for (int ks2 = 0; ks2 < 2; ++ks2) {
      int boA = l15 * 128 + (((ks2 * 4 + l4) ^ (l15 & 7)) * 16);
      bf16x8 pa = __builtin_bit_cast(bf16x8, *(const u32x4*)(pbase + boA));
      #pragma unroll
      for (int nf2 = 0; nf2 < 8; ++nf2) {
        int d = nf2 * 16 + l15;
        int boB = d * 128 + (((ks2 * 4 + l4) ^ (d & 7)) * 16);
        bf16x8 vf = __builtin_bit_cast(bf16x8, *(const u32x4*)((const char*)Vsm + boB));
        yacc[nf2] = mfma16(pa, vf, yacc[nf2]);
      }
    }
  }

  // normalize + write y (bf16)
  #pragma unroll
  for (int nf2 = 0; nf2 < 8; ++nf2)
    #pragma unroll
    for (int rg = 0; rg < 4; ++rg) {
      int r = qt * 64 + wid * 16 + l4 * 4 + rg;
      float v = yacc[nf2][rg] / lrow[rg];
      yb[(tokb + r) * (size_t)C_DIM + h * HD + nf2 * 16 + l15] = f2bf(v);
    }
}

// ---------------- launch ----------------
extern "C" void kernel_launch(void* const* d_in, const int* in_sizes, int n_in,
                              void* d_out, int out_size, void* d_ws, size_t ws_size,
                              hipStream_t stream) {
  const float* x    = (const float*)d_in[0];
  const float* cosb = (const float*)d_in[1];
  const float* sinb = (const float*)d_in[2];
  const float* wq   = (const float*)d_in[3];
  const float* wk   = (const float*)d_in[4];
  const float* wv   = (const float*)d_in[5];
  const float* wo   = (const float*)d_in[6];
  const int*   wsz  = (const int*)d_in[7];

  char* ws = (char*)d_ws;
  u16* xb    = (u16*)(ws);                       // 8M  elems (16 MB)
  u16* qkvb  = (u16*)(ws + (size_t)16777216);    // 12M elems (24 MB)
  u16* wqkvb = (u16*)(ws + (size_t)41943040);    // 6M  elems (12 MB), [3072][2048]
  u16* wob   = (u16*)(ws + (size_t)54525952);    // 4M  elems (8 MB),  [2048][2048]
  u16* ybuf  = (u16*)(ws + (size_t)62914560);    // 8M  elems (16 MB)

  cast_x_kernel<<<8192, 256, 0, stream>>>(x, xb, MTOK * C_DIM);
  transpose_cast_kernel<<<dim3(32, 32), 256, 0, stream>>>(wq, wqkvb, 2048, 2048);
  transpose_cast_kernel<<<dim3(8, 32), 256, 0, stream>>>(wk, wqkvb + (size_t)2048 * 2048, 2048, 512);
  transpose_cast_kernel<<<dim3(8, 32), 256, 0, stream>>>(wv, wqkvb + (size_t)2560 * 2048, 2048, 512);
  transpose_cast_kernel<<<dim3(32, 32), 256, 0, stream>>>(wo, wob, 2048, 2048);

  gemm_bt_kernel<1><<<dim3(NQKV / 128, MTOK / 128), 256, 0, stream>>>(xb, wqkvb, qkvb, MTOK, NQKV, C_DIM);
  rope_rms_kernel<<<(MTOK * (H_Q + H_KV)) / 4, 256, 0, stream>>>(qkvb, cosb, sinb);
  attn_kernel<<<B_DIM * H_Q * (T_DIM / 64), 256, 0, stream>>>(qkvb, ybuf, wsz);
  gemm_bt_kernel<0><<<dim3(C_DIM / 128, MTOK / 128), 256, 0, stream>>>(ybuf, wob, d_out, MTOK, C_DIM, C_DIM);
}